// Round 9
// baseline (476.946 us; speedup 1.0000x reference)
//
#include <hip/hip_runtime.h>
#include <hip/hip_bf16.h>

#define N_NODES 100000
#define N_EDGES 3200000
#define DIM 256
#define BN_EPS 1e-5f
#define BROWS 256
#define NBUCK ((N_NODES + BROWS - 1) / BROWS)   // 391
#define BIN_BLOCKS 512
#define EPB (N_EDGES / BIN_BLOCKS)              // 6250 exact
#define RPW 4                                   // rows per wave in spmm
#define NPART 64                                // stat partial buffers
#define CAP 10240                               // bucket capacity (mean 8185, +22 sigma)

typedef __attribute__((ext_vector_type(8))) short short8v;
typedef __attribute__((ext_vector_type(8))) unsigned short u16x8;
typedef __attribute__((ext_vector_type(4))) float f32x4;

__device__ __forceinline__ float b2f(unsigned short h) {
    return __uint_as_float(((unsigned int)h) << 16);
}
__device__ __forceinline__ unsigned short f2b(float f) {
    unsigned int u = __float_as_uint(f);
    unsigned int rounded = u + 0x7FFF + ((u >> 16) & 1);
    return (unsigned short)(rounded >> 16);
}

// ---------------- W -> fragment-ready bf16 layout -------------------------
__global__ __launch_bounds__(256) void wfrag_kernel(const float* __restrict__ W,
                                                    unsigned short* __restrict__ wfrag) {
    const int t = blockIdx.x * 256 + threadIdx.x;
    const int e = t & 7;
    const int l = (t >> 3) & 63;
    const int frag = t >> 9;
    const int nt = frag >> 3;
    const int ks = frag & 7;
    const int k = ks * 32 + ((l >> 4) << 3) + e;
    const int c = nt * 16 + (l & 15);
    wfrag[t] = f2b(W[k * DIM + c]);
}

// ---------------- GEMM via MFMA: zb = bf16( x @ W ) -----------------------
// R9 change: epilogue was 64 scalar 2B global stores per wave (each instr
// scatters 64 lanes x 2B across 16 rows @ 512B stride — worst-case
// coalescing; 400K store instrs total, ~32B useful per touched line).
// Now: stage the 16x256 tile in LDS (row stride 264 to soften ds_write
// conflicts), one __syncthreads, then 8 x ushort8 stores per lane = rows
// written as contiguous 1KB segments (8 coalesced instrs/wave).
// Early-return removed for barrier safety: OOR waves clamp to last tile
// (identical recompute -> benign duplicate store of identical bytes).
__global__ __launch_bounds__(256) void gemm_mfma_kernel(const float* __restrict__ x,
                                                        const unsigned short* __restrict__ wfrag,
                                                        unsigned short* __restrict__ zb) {
    __shared__ __attribute__((aligned(16))) unsigned short tile[4][16][264];
    const int w = threadIdx.x >> 6;
    int wid = (blockIdx.x * blockDim.x + threadIdx.x) >> 6;
    if (wid > N_NODES / 16 - 1) wid = N_NODES / 16 - 1;   // clamp, no early return
    const int lane = threadIdx.x & 63;
    const int m0 = wid * 16;

    const int arow = m0 + (lane & 15);
    const int kb = (lane >> 4) << 3;
    const float* xrow = x + (size_t)arow * DIM + kb;
    short8v af[8];
    #pragma unroll
    for (int ks = 0; ks < 8; ++ks) {
        const float4 a0 = *(const float4*)(xrow + ks * 32);
        const float4 a1 = *(const float4*)(xrow + ks * 32 + 4);
        short8v f;
        f[0] = (short)f2b(a0.x); f[1] = (short)f2b(a0.y);
        f[2] = (short)f2b(a0.z); f[3] = (short)f2b(a0.w);
        f[4] = (short)f2b(a1.x); f[5] = (short)f2b(a1.y);
        f[6] = (short)f2b(a1.z); f[7] = (short)f2b(a1.w);
        af[ks] = f;
    }

    const int r0 = (lane >> 4) << 2;
    const int dcol = lane & 15;
    unsigned short* tw = &tile[w][0][0];
    for (int nt = 0; nt < 16; ++nt) {
        f32x4 acc = {0.f, 0.f, 0.f, 0.f};
        const unsigned short* wp = wfrag + ((size_t)(nt * 8) * 64 + lane) * 8;
        #pragma unroll
        for (int ks = 0; ks < 8; ++ks) {
            const short8v bf = *(const short8v*)(wp + (size_t)ks * 64 * 8);
            acc = __builtin_amdgcn_mfma_f32_16x16x32_bf16(af[ks], bf, acc, 0, 0, 0);
        }
        const int c = nt * 16 + dcol;
        tw[(r0 + 0) * 264 + c] = f2b(acc[0]);
        tw[(r0 + 1) * 264 + c] = f2b(acc[1]);
        tw[(r0 + 2) * 264 + c] = f2b(acc[2]);
        tw[(r0 + 3) * 264 + c] = f2b(acc[3]);
    }
    __syncthreads();

    // coalesced write-out: 16 rows x 512B contiguous, 8 x 16B per lane
    unsigned short* zrow = zb + (size_t)m0 * DIM;
    #pragma unroll
    for (int i = 0; i < 8; ++i) {
        const int g = i * 64 + lane;         // ushort8 chunk id within tile
        const int r = g >> 5;                // 32 chunks per 256-col row
        const int c8 = (g & 31) << 3;
        *(u16x8*)(zrow + r * DIM + c8) = *(const u16x8*)(tw + r * 264 + c8);
    }
}

// ---------------- CSR stage 1: bin edges into FIXED-CAPACITY buckets ------
// No global histogram / scan needed: bucket b owns region [b*CAP, b*CAP+CAP).
// Block-local hist -> one atomicAdd per (block,bucket) reserves a chunk.
// entry: (row_local<<17 | col, val) packed in int2
__global__ __launch_bounds__(256) void bin_kernel(const int* __restrict__ rows,
                                                  const int* __restrict__ cols,
                                                  const float* __restrict__ vals,
                                                  int* bucketCnt,
                                                  int2* __restrict__ gBinned) {
    __shared__ int h[NBUCK];
    __shared__ int base[NBUCK];
    __shared__ int cur[NBUCK];
    const int t = threadIdx.x;
    const int e0 = blockIdx.x * EPB;
    for (int i = t; i < NBUCK; i += 256) h[i] = 0;
    __syncthreads();
    // pass 1: block-local bucket histogram
    for (int e = e0 + t; e < e0 + EPB; e += 256)
        atomicAdd(&h[rows[e] >> 8], 1);
    __syncthreads();
    // reserve chunks in the fixed regions
    for (int b = t; b < NBUCK; b += 256) {
        cur[b] = 0;
        if (h[b]) base[b] = atomicAdd(&bucketCnt[b], h[b]);
    }
    __syncthreads();
    // pass 2: place edges (rows/cols/vals are L1/L2-hot from pass 1)
    for (int e = e0 + t; e < e0 + EPB; e += 256) {
        const int r = rows[e];
        const int b = r >> 8;
        const int rk = atomicAdd(&cur[b], 1);
        int2 p;
        p.x = ((r & 255) << 17) | cols[e];
        p.y = __float_as_int(vals[e]);
        gBinned[(size_t)b * CAP + base[b] + rk] = p;
    }
}

// ---------------- CSR stage 2: fine sort within bucket + row_ptr/row_end --
__global__ __launch_bounds__(256) void fine_sort_kernel(const int* __restrict__ bucketCnt,
                                                        const int2* __restrict__ gBinned,
                                                        int* __restrict__ row_ptr,
                                                        int* __restrict__ row_end,
                                                        int2* __restrict__ finalE) {
    __shared__ int h[BROWS];
    __shared__ int s[BROWS];
    __shared__ int cur[BROWS];
    const int t = threadIdx.x;
    const int b = blockIdx.x;
    const int base0 = b * CAP;
    const int cnt = bucketCnt[b];
    h[t] = 0;
    __syncthreads();
    // pass 1: fine histogram over the 256 rows of this bucket
    for (int e = base0 + t; e < base0 + cnt; e += 256)
        atomicAdd(&h[gBinned[e].x >> 17], 1);
    __syncthreads();
    // inclusive scan of h into s
    s[t] = h[t];
    __syncthreads();
    for (int off = 1; off < BROWS; off <<= 1) {
        int x = (t >= off) ? s[t - off] : 0;
        __syncthreads();
        s[t] += x;
        __syncthreads();
    }
    const int excl = s[t] - h[t];
    const int grow = b * BROWS + t;
    if (grow < N_NODES) {
        row_ptr[grow] = base0 + excl;       // start of row within fixed region
        row_end[grow] = base0 + s[t];       // explicit end (padding breaks CSR identity)
    }
    cur[t] = excl;
    __syncthreads();
    // pass 2: scatter to final row-sorted positions (block-local region)
    for (int e = base0 + t; e < base0 + cnt; e += 256) {
        const int2 p = gBinned[e];
        const int rl = p.x >> 17;
        const int rk = atomicAdd(&cur[rl], 1);
        int2 q;
        q.x = p.x & 0x1FFFF;
        q.y = p.y;
        finalE[base0 + rk] = q;
    }
}

// ---------------- SpMM (CSR gather) + fused BN stats ----------------------
// FROZEN at R6/R8 best structure (241 us): RPW=4 rows/wave, readfirstlane'd
// bounds, 8-deep double-batch pipeline, predicated tail, nt out store, LDS
// stats + NPART global-atomic partials. Seven structural variants (R0-R8)
// converge on ~3.8-3.9 TB/s at FETCH ~765 MB = the fabric/LLC gather floor.
__global__ __launch_bounds__(256) void spmm_csr_kernel(const int* __restrict__ row_ptr,
                                                       const int* __restrict__ row_end,
                                                       const int2* __restrict__ pairs,
                                                       const unsigned short* __restrict__ zb,
                                                       float* __restrict__ out,
                                                       float* __restrict__ partials) {
    __shared__ float sdata[2 * DIM];
    const int t = threadIdx.x;
    sdata[t] = 0.f;
    sdata[t + 256] = 0.f;
    __syncthreads();

    const int wave = (blockIdx.x * 256 + t) >> 6;
    const int lane = t & 63;
    const int row0 = wave * RPW;              // grid exact: 6250 blocks * 4 waves * 4 rows = 100000

    float4 s  = make_float4(0.f, 0.f, 0.f, 0.f);
    float4 sq = make_float4(0.f, 0.f, 0.f, 0.f);

    for (int row = row0; row < row0 + RPW; ++row) {
        const int start = __builtin_amdgcn_readfirstlane(row_ptr[row]);
        const int end   = __builtin_amdgcn_readfirstlane(row_end[row]);
        float4 acc = make_float4(0.f, 0.f, 0.f, 0.f);
        int2 pA[8], pB[8];
        ushort4 mA[8], mB[8];

#define LOADX(P, M, EB) do { \
    _Pragma("unroll") for (int j = 0; j < 8; ++j) P[j] = pairs[(EB) + j]; \
    _Pragma("unroll") for (int j = 0; j < 8; ++j) \
        M[j] = ((const ushort4*)(zb + (size_t)P[j].x * DIM))[lane]; \
  } while (0)
#define FMAX(P, M) do { \
    _Pragma("unroll") for (int j = 0; j < 8; ++j) { \
        const float v = __int_as_float(P[j].y); \
        acc.x += v * b2f(M[j].x); \
        acc.y += v * b2f(M[j].y); \
        acc.z += v * b2f(M[j].z); \
        acc.w += v * b2f(M[j].w); \
    } \
  } while (0)

        const int nb = (end - start) >> 3;
        int e = start;
        if (nb) {
            LOADX(pA, mA, e); e += 8;
            int b = 1;
            for (; b + 1 < nb; b += 2) {
                LOADX(pB, mB, e); e += 8;   // B in flight while A is consumed
                FMAX(pA, mA);
                LOADX(pA, mA, e); e += 8;   // A in flight while B is consumed
                FMAX(pB, mB);
            }
            if (b < nb) {
                LOADX(pB, mB, e); e += 8;
                FMAX(pA, mA);
                FMAX(pB, mB);
            } else {
                FMAX(pA, mA);
            }
        }
        // predicated tail batch (0..7 edges), uniform branches
        const int rem = end - e;
        if (rem) {
            #pragma unroll
            for (int j = 0; j < 8; ++j) if (j < rem) pA[j] = pairs[e + j];
            #pragma unroll
            for (int j = 0; j < 8; ++j) if (j < rem)
                mA[j] = ((const ushort4*)(zb + (size_t)pA[j].x * DIM))[lane];
            #pragma unroll
            for (int j = 0; j < 8; ++j) if (j < rem) {
                const float v = __int_as_float(pA[j].y);
                acc.x += v * b2f(mA[j].x);
                acc.y += v * b2f(mA[j].y);
                acc.z += v * b2f(mA[j].z);
                acc.w += v * b2f(mA[j].w);
            }
        }
#undef LOADX
#undef FMAX

        // nontemporal (no-allocate) out store
        f32x4 st = {acc.x, acc.y, acc.z, acc.w};
        __builtin_nontemporal_store(st, (f32x4*)(out + (size_t)row * DIM) + lane);

        s.x += acc.x; s.y += acc.y; s.z += acc.z; s.w += acc.w;
        sq.x += acc.x * acc.x; sq.y += acc.y * acc.y;
        sq.z += acc.z * acc.z; sq.w += acc.w * acc.w;
    }

    const int c0 = lane * 4;
    atomicAdd(&sdata[c0 + 0], s.x);
    atomicAdd(&sdata[c0 + 1], s.y);
    atomicAdd(&sdata[c0 + 2], s.z);
    atomicAdd(&sdata[c0 + 3], s.w);
    atomicAdd(&sdata[256 + c0 + 0], sq.x);
    atomicAdd(&sdata[256 + c0 + 1], sq.y);
    atomicAdd(&sdata[256 + c0 + 2], sq.z);
    atomicAdd(&sdata[256 + c0 + 3], sq.w);
    __syncthreads();

    float* pb = partials + (size_t)(blockIdx.x & (NPART - 1)) * (2 * DIM);
    atomicAdd(&pb[t], sdata[t]);
    atomicAdd(&pb[t + 256], sdata[t + 256]);
}

// ---------------- finalize: reduce partials, scale/bias per column --------
__global__ __launch_bounds__(256) void finalize_kernel(const float* __restrict__ partials,
                                                       const float* __restrict__ gamma,
                                                       const float* __restrict__ beta,
                                                       float* __restrict__ sb) {
    const int c = threadIdx.x;
    float s = 0.f, ssq = 0.f;
    for (int b = 0; b < NPART; ++b) {
        s   += partials[b * (2 * DIM) + c];
        ssq += partials[b * (2 * DIM) + 256 + c];
    }
    const float inv_n = 1.0f / (float)N_NODES;
    const float mean = s * inv_n;
    float var = ssq * inv_n - mean * mean;
    const float rstd = rsqrtf(var + BN_EPS);
    const float scale = rstd * gamma[c];
    sb[c] = scale;
    sb[DIM + c] = beta[c] - mean * scale;
}

// ---------------- normalize + ReLU (in-place on d_out) --------------------
#define NORM_BLOCKS 2048
__global__ __launch_bounds__(256) void norm_kernel(float* __restrict__ out,
                                                   const float* __restrict__ sb) {
    // compile-time stride (multiple of 64) => (idx & 63) == (threadIdx.x & 63)
    // for every iteration => scale/bias hoist to registers.
    const int c0 = (threadIdx.x & 63) * 4;
    const float s0 = sb[c0 + 0], s1 = sb[c0 + 1], s2 = sb[c0 + 2], s3 = sb[c0 + 3];
    const float b0 = sb[DIM + c0 + 0], b1 = sb[DIM + c0 + 1];
    const float b2 = sb[DIM + c0 + 2], b3 = sb[DIM + c0 + 3];
    const int nvec = N_NODES * (DIM / 4);
    for (int idx = blockIdx.x * 256 + threadIdx.x; idx < nvec; idx += NORM_BLOCKS * 256) {
        float4 a = ((float4*)out)[idx];
        float4 o;
        o.x = fmaxf(fmaf(a.x, s0, b0), 0.f);
        o.y = fmaxf(fmaf(a.y, s1, b1), 0.f);
        o.z = fmaxf(fmaf(a.z, s2, b2), 0.f);
        o.w = fmaxf(fmaf(a.w, s3, b3), 0.f);
        ((float4*)out)[idx] = o;
    }
}

extern "C" void kernel_launch(void* const* d_in, const int* in_sizes, int n_in,
                              void* d_out, int out_size, void* d_ws, size_t ws_size,
                              hipStream_t stream) {
    const float* x         = (const float*)d_in[0];
    const int*   edge_rows = (const int*)d_in[1];
    const int*   edge_cols = (const int*)d_in[2];
    const float* edge_vals = (const float*)d_in[3];
    const float* weight    = (const float*)d_in[4];
    const float* gamma     = (const float*)d_in[5];
    const float* beta      = (const float*)d_in[6];
    float* out = (float*)d_out;

    // workspace layout (~84 MB). gBinned (32 MB, dead after fine_sort)
    // OVERLAYS zb (51.2 MB, written by gemm which runs after fine_sort).
    unsigned short* zb    = (unsigned short*)d_ws;             // 51.2 MB
    int2*  gBinned  = (int2*)d_ws;                             // 391*CAP*8 = 32 MB (union with zb)
    unsigned short* wfrag = zb + (size_t)N_NODES * DIM;        // 128 KB
    int2*  finalE   = (int2*)(wfrag + DIM * DIM);              // 391*CAP*8 = 32 MB
    int*   row_ptr  = (int*)(finalE + (size_t)NBUCK * CAP);    // N ints
    int*   row_end  = row_ptr + N_NODES;                       // N ints
    int*   bucketCnt = row_end + N_NODES;                      // 391
    float* partials = (float*)(bucketCnt + NBUCK);             // 64*512 f32 = 128 KB
    float* sb       = partials + NPART * 2 * DIM;              // 512 f32

    // zero bucket cursors + stat partials (contiguous)
    hipMemsetAsync(bucketCnt, 0, (NBUCK + NPART * 2 * DIM) * sizeof(int), stream);

    // CSR prep first (gBinned lives in zb's space, dead before gemm)
    bin_kernel<<<BIN_BLOCKS, 256, 0, stream>>>(edge_rows, edge_cols, edge_vals, bucketCnt, gBinned);
    fine_sort_kernel<<<NBUCK, 256, 0, stream>>>(bucketCnt, gBinned, row_ptr, row_end, finalE);

    wfrag_kernel<<<DIM * DIM / 256, 256, 0, stream>>>(weight, wfrag);
    gemm_mfma_kernel<<<(N_NODES / 16 + 3) / 4, 256, 0, stream>>>(x, wfrag, zb);

    // spmm + fused BN stats: 6250 blocks * 4 waves * 4 rows = 100000 rows exact
    spmm_csr_kernel<<<N_NODES / (RPW * 4), 256, 0, stream>>>(row_ptr, row_end, finalE, zb, out, partials);

    finalize_kernel<<<1, 256, 0, stream>>>(partials, gamma, beta, sb);
    norm_kernel<<<NORM_BLOCKS, 256, 0, stream>>>(out, sb);
}

// Round 10
// 436.452 us; speedup vs baseline: 1.0928x; 1.0928x over previous
//
#include <hip/hip_runtime.h>
#include <hip/hip_bf16.h>

#define N_NODES 100000
#define N_EDGES 3200000
#define DIM 256
#define BN_EPS 1e-5f
#define BROWS 256
#define NBUCK ((N_NODES + BROWS - 1) / BROWS)   // 391
#define BIN_BLOCKS 512
#define EPB (N_EDGES / BIN_BLOCKS)              // 6250 exact
#define RPW 4                                   // rows per wave in spmm
#define NPART 64                                // stat partial buffers
#define CAP 10240                               // bucket capacity (mean 8185, +22 sigma)
#define WFRAG_BLOCKS (DIM * DIM / 256)          // 256
#define GEMM_BLOCKS ((N_NODES / 16 + 3) / 4)    // 1563

typedef __attribute__((ext_vector_type(8))) short short8v;
typedef __attribute__((ext_vector_type(4))) float f32x4;

__device__ __forceinline__ float b2f(unsigned short h) {
    return __uint_as_float(((unsigned int)h) << 16);
}
__device__ __forceinline__ unsigned short f2b(float f) {
    unsigned int u = __float_as_uint(f);
    unsigned int rounded = u + 0x7FFF + ((u >> 16) & 1);
    return (unsigned short)(rounded >> 16);
}

// ============ Kernel A: bin (blocks 0..511)  ||  wfrag (blocks 512..767) ===
// The two tasks are fully independent; merging removes a dispatch and lets
// the small wfrag ride along free. Bodies are R8-verbatim.
__global__ __launch_bounds__(256) void bin_wfrag_kernel(const int* __restrict__ rows,
                                                        const int* __restrict__ cols,
                                                        const float* __restrict__ vals,
                                                        int* bucketCnt,
                                                        int2* __restrict__ gBinned,
                                                        const float* __restrict__ W,
                                                        unsigned short* __restrict__ wfrag) {
    __shared__ int h[NBUCK];
    __shared__ int base[NBUCK];
    __shared__ int cur[NBUCK];
    const int t = threadIdx.x;

    if (blockIdx.x >= BIN_BLOCKS) {
        // ---- wfrag: W -> fragment-ready bf16 layout ----
        const int g = (blockIdx.x - BIN_BLOCKS) * 256 + t;
        const int e = g & 7;
        const int l = (g >> 3) & 63;
        const int frag = g >> 9;
        const int nt = frag >> 3;
        const int ks = frag & 7;
        const int k = ks * 32 + ((l >> 4) << 3) + e;
        const int c = nt * 16 + (l & 15);
        wfrag[g] = f2b(W[k * DIM + c]);
        return;
    }

    // ---- bin: fixed-capacity bucket scatter ----
    const int e0 = blockIdx.x * EPB;
    for (int i = t; i < NBUCK; i += 256) h[i] = 0;
    __syncthreads();
    for (int e = e0 + t; e < e0 + EPB; e += 256)
        atomicAdd(&h[rows[e] >> 8], 1);
    __syncthreads();
    for (int b = t; b < NBUCK; b += 256) {
        cur[b] = 0;
        if (h[b]) base[b] = atomicAdd(&bucketCnt[b], h[b]);
    }
    __syncthreads();
    for (int e = e0 + t; e < e0 + EPB; e += 256) {
        const int r = rows[e];
        const int b = r >> 8;
        const int rk = atomicAdd(&cur[b], 1);
        int2 p;
        p.x = ((r & 255) << 17) | cols[e];
        p.y = __float_as_int(vals[e]);
        gBinned[(size_t)b * CAP + base[b] + rk] = p;
    }
}

// ============ Kernel B: fine_sort (blocks 0..390) || gemm (391..1953) ======
// Independent chains: fine_sort consumes bin's output; gemm consumes wfrag.
// Both complete in kernel A. fine_sort is VMEM/LDS-atomic-bound, gemm is
// MFMA-bound -> they co-schedule on complementary pipes. Bodies R8-verbatim.
__global__ __launch_bounds__(256) void sort_gemm_kernel(const int* __restrict__ bucketCnt,
                                                        const int2* __restrict__ gBinned,
                                                        int* __restrict__ row_ptr,
                                                        int* __restrict__ row_end,
                                                        int2* __restrict__ finalE,
                                                        const float* __restrict__ x,
                                                        const unsigned short* __restrict__ wfrag,
                                                        unsigned short* __restrict__ zb) {
    __shared__ int h[BROWS];
    __shared__ int s[BROWS];
    __shared__ int cur[BROWS];
    const int t = threadIdx.x;

    if (blockIdx.x >= NBUCK) {
        // ---- gemm via MFMA: zb = bf16( x @ W ) ----
        const int wid = ((blockIdx.x - NBUCK) * 256 + t) >> 6;
        const int lane = t & 63;
        if (wid >= N_NODES / 16) return;
        const int m0 = wid * 16;

        const int arow = m0 + (lane & 15);
        const int kb = (lane >> 4) << 3;
        const float* xrow = x + (size_t)arow * DIM + kb;
        short8v af[8];
        #pragma unroll
        for (int ks = 0; ks < 8; ++ks) {
            const float4 a0 = *(const float4*)(xrow + ks * 32);
            const float4 a1 = *(const float4*)(xrow + ks * 32 + 4);
            short8v f;
            f[0] = (short)f2b(a0.x); f[1] = (short)f2b(a0.y);
            f[2] = (short)f2b(a0.z); f[3] = (short)f2b(a0.w);
            f[4] = (short)f2b(a1.x); f[5] = (short)f2b(a1.y);
            f[6] = (short)f2b(a1.z); f[7] = (short)f2b(a1.w);
            af[ks] = f;
        }

        const int drow0 = m0 + ((lane >> 4) << 2);
        const int dcol = lane & 15;
        for (int nt = 0; nt < 16; ++nt) {
            f32x4 acc = {0.f, 0.f, 0.f, 0.f};
            const unsigned short* wp = wfrag + ((size_t)(nt * 8) * 64 + lane) * 8;
            #pragma unroll
            for (int ks = 0; ks < 8; ++ks) {
                const short8v bf = *(const short8v*)(wp + (size_t)ks * 64 * 8);
                acc = __builtin_amdgcn_mfma_f32_16x16x32_bf16(af[ks], bf, acc, 0, 0, 0);
            }
            unsigned short* zp = zb + (size_t)drow0 * DIM + nt * 16 + dcol;
            zp[0]       = f2b(acc[0]);
            zp[DIM]     = f2b(acc[1]);
            zp[2 * DIM] = f2b(acc[2]);
            zp[3 * DIM] = f2b(acc[3]);
        }
        return;
    }

    // ---- fine sort within bucket + row_ptr/row_end ----
    const int b = blockIdx.x;
    const int base0 = b * CAP;
    const int cnt = bucketCnt[b];
    h[t] = 0;
    __syncthreads();
    for (int e = base0 + t; e < base0 + cnt; e += 256)
        atomicAdd(&h[gBinned[e].x >> 17], 1);
    __syncthreads();
    s[t] = h[t];
    __syncthreads();
    for (int off = 1; off < BROWS; off <<= 1) {
        int x2 = (t >= off) ? s[t - off] : 0;
        __syncthreads();
        s[t] += x2;
        __syncthreads();
    }
    const int excl = s[t] - h[t];
    const int grow = b * BROWS + t;
    if (grow < N_NODES) {
        row_ptr[grow] = base0 + excl;
        row_end[grow] = base0 + s[t];
    }
    cur[t] = excl;
    __syncthreads();
    for (int e = base0 + t; e < base0 + cnt; e += 256) {
        const int2 p = gBinned[e];
        const int rl = p.x >> 17;
        const int rk = atomicAdd(&cur[rl], 1);
        int2 q;
        q.x = p.x & 0x1FFFF;
        q.y = p.y;
        finalE[base0 + rk] = q;
    }
}

// ---------------- SpMM (CSR gather) + fused BN stats ----------------------
// FROZEN at R6/R8 best structure (241 us): RPW=4 rows/wave, readfirstlane'd
// bounds, 8-deep double-batch pipeline, predicated tail, nt out store, LDS
// stats + NPART global-atomic partials. Seven structural variants (R0-R8)
// converge on ~3.8-3.9 TB/s at FETCH ~765 MB = the fabric/LLC gather floor.
__global__ __launch_bounds__(256) void spmm_csr_kernel(const int* __restrict__ row_ptr,
                                                       const int* __restrict__ row_end,
                                                       const int2* __restrict__ pairs,
                                                       const unsigned short* __restrict__ zb,
                                                       float* __restrict__ out,
                                                       float* __restrict__ partials) {
    __shared__ float sdata[2 * DIM];
    const int t = threadIdx.x;
    sdata[t] = 0.f;
    sdata[t + 256] = 0.f;
    __syncthreads();

    const int wave = (blockIdx.x * 256 + t) >> 6;
    const int lane = t & 63;
    const int row0 = wave * RPW;              // grid exact: 6250 blocks * 4 waves * 4 rows = 100000

    float4 s  = make_float4(0.f, 0.f, 0.f, 0.f);
    float4 sq = make_float4(0.f, 0.f, 0.f, 0.f);

    for (int row = row0; row < row0 + RPW; ++row) {
        const int start = __builtin_amdgcn_readfirstlane(row_ptr[row]);
        const int end   = __builtin_amdgcn_readfirstlane(row_end[row]);
        float4 acc = make_float4(0.f, 0.f, 0.f, 0.f);
        int2 pA[8], pB[8];
        ushort4 mA[8], mB[8];

#define LOADX(P, M, EB) do { \
    _Pragma("unroll") for (int j = 0; j < 8; ++j) P[j] = pairs[(EB) + j]; \
    _Pragma("unroll") for (int j = 0; j < 8; ++j) \
        M[j] = ((const ushort4*)(zb + (size_t)P[j].x * DIM))[lane]; \
  } while (0)
#define FMAX(P, M) do { \
    _Pragma("unroll") for (int j = 0; j < 8; ++j) { \
        const float v = __int_as_float(P[j].y); \
        acc.x += v * b2f(M[j].x); \
        acc.y += v * b2f(M[j].y); \
        acc.z += v * b2f(M[j].z); \
        acc.w += v * b2f(M[j].w); \
    } \
  } while (0)

        const int nb = (end - start) >> 3;
        int e = start;
        if (nb) {
            LOADX(pA, mA, e); e += 8;
            int b = 1;
            for (; b + 1 < nb; b += 2) {
                LOADX(pB, mB, e); e += 8;   // B in flight while A is consumed
                FMAX(pA, mA);
                LOADX(pA, mA, e); e += 8;   // A in flight while B is consumed
                FMAX(pB, mB);
            }
            if (b < nb) {
                LOADX(pB, mB, e); e += 8;
                FMAX(pA, mA);
                FMAX(pB, mB);
            } else {
                FMAX(pA, mA);
            }
        }
        // predicated tail batch (0..7 edges), uniform branches
        const int rem = end - e;
        if (rem) {
            #pragma unroll
            for (int j = 0; j < 8; ++j) if (j < rem) pA[j] = pairs[e + j];
            #pragma unroll
            for (int j = 0; j < 8; ++j) if (j < rem)
                mA[j] = ((const ushort4*)(zb + (size_t)pA[j].x * DIM))[lane];
            #pragma unroll
            for (int j = 0; j < 8; ++j) if (j < rem) {
                const float v = __int_as_float(pA[j].y);
                acc.x += v * b2f(mA[j].x);
                acc.y += v * b2f(mA[j].y);
                acc.z += v * b2f(mA[j].z);
                acc.w += v * b2f(mA[j].w);
            }
        }
#undef LOADX
#undef FMAX

        // nontemporal (no-allocate) out store
        f32x4 st = {acc.x, acc.y, acc.z, acc.w};
        __builtin_nontemporal_store(st, (f32x4*)(out + (size_t)row * DIM) + lane);

        s.x += acc.x; s.y += acc.y; s.z += acc.z; s.w += acc.w;
        sq.x += acc.x * acc.x; sq.y += acc.y * acc.y;
        sq.z += acc.z * acc.z; sq.w += acc.w * acc.w;
    }

    const int c0 = lane * 4;
    atomicAdd(&sdata[c0 + 0], s.x);
    atomicAdd(&sdata[c0 + 1], s.y);
    atomicAdd(&sdata[c0 + 2], s.z);
    atomicAdd(&sdata[c0 + 3], s.w);
    atomicAdd(&sdata[256 + c0 + 0], sq.x);
    atomicAdd(&sdata[256 + c0 + 1], sq.y);
    atomicAdd(&sdata[256 + c0 + 2], sq.z);
    atomicAdd(&sdata[256 + c0 + 3], sq.w);
    __syncthreads();

    float* pb = partials + (size_t)(blockIdx.x & (NPART - 1)) * (2 * DIM);
    atomicAdd(&pb[t], sdata[t]);
    atomicAdd(&pb[t + 256], sdata[t + 256]);
}

// ---------------- finalize: reduce partials, scale/bias per column --------
__global__ __launch_bounds__(256) void finalize_kernel(const float* __restrict__ partials,
                                                       const float* __restrict__ gamma,
                                                       const float* __restrict__ beta,
                                                       float* __restrict__ sb) {
    const int c = threadIdx.x;
    float s = 0.f, ssq = 0.f;
    for (int b = 0; b < NPART; ++b) {
        s   += partials[b * (2 * DIM) + c];
        ssq += partials[b * (2 * DIM) + 256 + c];
    }
    const float inv_n = 1.0f / (float)N_NODES;
    const float mean = s * inv_n;
    float var = ssq * inv_n - mean * mean;
    const float rstd = rsqrtf(var + BN_EPS);
    const float scale = rstd * gamma[c];
    sb[c] = scale;
    sb[DIM + c] = beta[c] - mean * scale;
}

// ---------------- normalize + ReLU (in-place on d_out) --------------------
#define NORM_BLOCKS 2048
__global__ __launch_bounds__(256) void norm_kernel(float* __restrict__ out,
                                                   const float* __restrict__ sb) {
    // compile-time stride (multiple of 64) => (idx & 63) == (threadIdx.x & 63)
    // for every iteration => scale/bias hoist to registers.
    const int c0 = (threadIdx.x & 63) * 4;
    const float s0 = sb[c0 + 0], s1 = sb[c0 + 1], s2 = sb[c0 + 2], s3 = sb[c0 + 3];
    const float b0 = sb[DIM + c0 + 0], b1 = sb[DIM + c0 + 1];
    const float b2 = sb[DIM + c0 + 2], b3 = sb[DIM + c0 + 3];
    const int nvec = N_NODES * (DIM / 4);
    for (int idx = blockIdx.x * 256 + threadIdx.x; idx < nvec; idx += NORM_BLOCKS * 256) {
        float4 a = ((float4*)out)[idx];
        float4 o;
        o.x = fmaxf(fmaf(a.x, s0, b0), 0.f);
        o.y = fmaxf(fmaf(a.y, s1, b1), 0.f);
        o.z = fmaxf(fmaf(a.z, s2, b2), 0.f);
        o.w = fmaxf(fmaf(a.w, s3, b3), 0.f);
        ((float4*)out)[idx] = o;
    }
}

extern "C" void kernel_launch(void* const* d_in, const int* in_sizes, int n_in,
                              void* d_out, int out_size, void* d_ws, size_t ws_size,
                              hipStream_t stream) {
    const float* x         = (const float*)d_in[0];
    const int*   edge_rows = (const int*)d_in[1];
    const int*   edge_cols = (const int*)d_in[2];
    const float* edge_vals = (const float*)d_in[3];
    const float* weight    = (const float*)d_in[4];
    const float* gamma     = (const float*)d_in[5];
    const float* beta      = (const float*)d_in[6];
    float* out = (float*)d_out;

    // workspace layout (~84 MB). gBinned (32 MB, dead after fine_sort)
    // OVERLAYS zb (51.2 MB). NOTE: gemm now runs CONCURRENTLY with
    // fine_sort in kernel B — but gBinned lives in zb[0 .. 16M ushorts) and
    // is only read by fine_sort while gemm writes zb... CONFLICT? No:
    // gBinned must NOT overlay zb anymore. Give gBinned its own region.
    unsigned short* zb    = (unsigned short*)d_ws;             // 51.2 MB
    unsigned short* wfrag = zb + (size_t)N_NODES * DIM;        // 128 KB
    int2*  gBinned  = (int2*)(wfrag + DIM * DIM);              // 32 MB (own region)
    int2*  finalE   = gBinned + (size_t)NBUCK * CAP;           // 32 MB
    int*   row_ptr  = (int*)(finalE + (size_t)NBUCK * CAP);    // N ints
    int*   row_end  = row_ptr + N_NODES;                       // N ints
    int*   bucketCnt = row_end + N_NODES;                      // 391
    float* partials = (float*)(bucketCnt + NBUCK);             // 64*512 f32 = 128 KB
    float* sb       = partials + NPART * 2 * DIM;              // 512 f32

    // zero bucket cursors + stat partials (contiguous)
    hipMemsetAsync(bucketCnt, 0, (NBUCK + NPART * 2 * DIM) * sizeof(int), stream);

    // Kernel A: bin (512 blocks) || wfrag (256 blocks) — independent tasks
    bin_wfrag_kernel<<<BIN_BLOCKS + WFRAG_BLOCKS, 256, 0, stream>>>(
        edge_rows, edge_cols, edge_vals, bucketCnt, gBinned, weight, wfrag);

    // Kernel B: fine_sort (391 blocks) || gemm (1563 blocks) — independent
    // chains, complementary pipes (LDS-atomics vs MFMA) -> true overlap
    sort_gemm_kernel<<<NBUCK + GEMM_BLOCKS, 256, 0, stream>>>(
        bucketCnt, gBinned, row_ptr, row_end, finalE, x, wfrag, zb);

    // spmm + fused BN stats: 6250 blocks * 4 waves * 4 rows = 100000 rows exact
    spmm_csr_kernel<<<N_NODES / (RPW * 4), 256, 0, stream>>>(row_ptr, row_end, finalE, zb, out, partials);

    finalize_kernel<<<1, 256, 0, stream>>>(partials, gamma, beta, sb);
    norm_kernel<<<NORM_BLOCKS, 256, 0, stream>>>(out, sb);
}